// Round 1
// baseline (728.351 us; speedup 1.0000x reference)
//
#include <hip/hip_runtime.h>
#include <math.h>

// PhaseRefinement fused kernel.
// out = x + LN(c*x)*gamma + beta, where c is a per-row scalar derived from
// 32 dot products of x with W_refine/W_out rows.
// LN(c*x) simplifies: normed = gamma*(alpha*x - alpha*mu) + beta,
//   alpha = c * rsqrt(c^2*var + 1e-5), mu/var = row stats of x.

constexpr int Dh    = 4096;   // hidden dim
constexpr int Ph    = 16;     // planes
constexpr int NPL   = 32;     // 2*P dot products per row
constexpr int CHUNK = 512;    // columns per LDS W-chunk
constexpr int NCHUNK = Dh / CHUNK;  // 8
constexpr int RPB   = 8;      // rows per block (2 per wave)
constexpr int BLOCK = 256;    // 4 waves

__global__ __launch_bounds__(BLOCK, 2)
void phase_fused(const float* __restrict__ x,
                 const float* __restrict__ Wr,
                 const float* __restrict__ br,
                 const float* __restrict__ Wo,
                 const float* __restrict__ bo,
                 const float* __restrict__ gamma,
                 const float* __restrict__ beta,
                 float* __restrict__ out)
{
    __shared__ float W_lds[NPL][CHUNK];      // 64 KB: W column-chunk, all 32 planes
    __shared__ float dots_lds[RPB][NPL];
    __shared__ float stats_lds[RPB][2];      // sumx, sumx2
    __shared__ float scale_lds[RPB][2];      // alpha, alpha*mu

    const int t    = threadIdx.x;
    const int wv   = t >> 6;
    const int lane = t & 63;

    const size_t rowbase = (size_t)blockIdx.x * RPB;
    const int r0 = wv * 2;    // this wave owns rows r0, r0+1 (register-blocked)

    const float* x0 = x + (rowbase + r0) * (size_t)Dh;
    const float* x1 = x + (rowbase + r0 + 1) * (size_t)Dh;

    float acc0[NPL];
    float acc1[NPL];
#pragma unroll
    for (int p = 0; p < NPL; ++p) { acc0[p] = 0.f; acc1[p] = 0.f; }
    float sx0 = 0.f, sxx0 = 0.f, sx1 = 0.f, sxx1 = 0.f;

    for (int c = 0; c < NCHUNK; ++c) {
        __syncthreads();  // protect W_lds readers from previous iteration
        // Stage W chunk: planes 0..15 from W_refine, 16..31 from W_out.
        // flat = i*256+t -> plane p = flat/128, float4 index j = flat%128.
#pragma unroll
        for (int i = 0; i < 16; ++i) {
            int flat = i * BLOCK + t;
            int p = flat >> 7;
            int j = flat & 127;
            const float* srcrow = (p < Ph) ? (Wr + (size_t)p * Dh)
                                           : (Wo + (size_t)(p - Ph) * Dh);
            float4 v = *(const float4*)(srcrow + c * CHUNK + j * 4);
            *(float4*)&W_lds[p][j * 4] = v;
        }
        // x loads for this chunk: lane covers cols lane*4 and 256+lane*4
        const int cb = c * CHUNK + lane * 4;
        float4 xa0 = *(const float4*)(x0 + cb);
        float4 xb0 = *(const float4*)(x0 + cb + 256);
        float4 xa1 = *(const float4*)(x1 + cb);
        float4 xb1 = *(const float4*)(x1 + cb + 256);
        __syncthreads();  // staging visible

        sx0  += (xa0.x + xa0.y + xa0.z + xa0.w) + (xb0.x + xb0.y + xb0.z + xb0.w);
        sxx0 += xa0.x*xa0.x + xa0.y*xa0.y + xa0.z*xa0.z + xa0.w*xa0.w
              + xb0.x*xb0.x + xb0.y*xb0.y + xb0.z*xb0.z + xb0.w*xb0.w;
        sx1  += (xa1.x + xa1.y + xa1.z + xa1.w) + (xb1.x + xb1.y + xb1.z + xb1.w);
        sxx1 += xa1.x*xa1.x + xa1.y*xa1.y + xa1.z*xa1.z + xa1.w*xa1.w
              + xb1.x*xb1.x + xb1.y*xb1.y + xb1.z*xb1.z + xb1.w*xb1.w;

#pragma unroll
        for (int p = 0; p < NPL; ++p) {
            float4 wa = *(const float4*)&W_lds[p][lane * 4];
            float4 wb = *(const float4*)&W_lds[p][lane * 4 + 256];
            acc0[p] += xa0.x*wa.x + xa0.y*wa.y + xa0.z*wa.z + xa0.w*wa.w
                     + xb0.x*wb.x + xb0.y*wb.y + xb0.z*wb.z + xb0.w*wb.w;
            acc1[p] += xa1.x*wa.x + xa1.y*wa.y + xa1.z*wa.z + xa1.w*wa.w
                     + xb1.x*wb.x + xb1.y*wb.y + xb1.z*wb.z + xb1.w*wb.w;
        }
    }

    // Butterfly reduce across the 64 lanes (each dot spans the full row).
#pragma unroll
    for (int p = 0; p < NPL; ++p) {
        float v0 = acc0[p], v1 = acc1[p];
#pragma unroll
        for (int m = 1; m < 64; m <<= 1) {
            v0 += __shfl_xor(v0, m, 64);
            v1 += __shfl_xor(v1, m, 64);
        }
        if (lane == 0) { dots_lds[r0][p] = v0; dots_lds[r0 + 1][p] = v1; }
    }
#pragma unroll
    for (int m = 1; m < 64; m <<= 1) {
        sx0  += __shfl_xor(sx0, m, 64);
        sxx0 += __shfl_xor(sxx0, m, 64);
        sx1  += __shfl_xor(sx1, m, 64);
        sxx1 += __shfl_xor(sxx1, m, 64);
    }
    if (lane == 0) {
        stats_lds[r0][0] = sx0;  stats_lds[r0][1] = sxx0;
        stats_lds[r0 + 1][0] = sx1;  stats_lds[r0 + 1][1] = sxx1;
    }
    __syncthreads();

    // Per-row scalar phase (8 threads, one per row).
    if (t < RPB) {
        const int r = t;
        float s = 0.f;
#pragma unroll
        for (int p = 0; p < Ph; ++p) {
            float rp = tanhf(dots_lds[r][p]      + br[p]);
            float op = tanhf(dots_lds[r][Ph + p] + bo[p]);
            s += cosf((rp - op) * 3.14159265358979323846f);
        }
        float gain = log1pf(expf(s * (1.f / Ph) + 0.5f));   // softplus(resonance+0.5)
        float cm   = s * gain * (1.f / Ph);                  // per-row scalar c
        float mu   = stats_lds[r][0] * (1.f / Dh);
        float var  = stats_lds[r][1] * (1.f / Dh) - mu * mu;
        var = fmaxf(var, 0.f);
        float rstd  = rsqrtf(cm * cm * var + 1e-5f);
        float alpha = cm * rstd;
        scale_lds[r][0] = alpha;
        scale_lds[r][1] = alpha * mu;
    }
    __syncthreads();

    // Phase B: elementwise output. x rows re-read (should be L2-hot).
    for (int r = 0; r < RPB; ++r) {
        const float alpha = scale_lds[r][0];
        const float am    = scale_lds[r][1];
        const float* xr = x   + (rowbase + r) * (size_t)Dh;
        float* orow     = out + (rowbase + r) * (size_t)Dh;
#pragma unroll
        for (int i = 0; i < 4; ++i) {
            const int col = i * 1024 + t * 4;
            float4 xv = *(const float4*)(xr + col);
            float4 g  = *(const float4*)(gamma + col);
            float4 bb = *(const float4*)(beta + col);
            float4 o;
            o.x = xv.x + g.x * (alpha * xv.x - am) + bb.x;
            o.y = xv.y + g.y * (alpha * xv.y - am) + bb.y;
            o.z = xv.z + g.z * (alpha * xv.z - am) + bb.z;
            o.w = xv.w + g.w * (alpha * xv.w - am) + bb.w;
            *(float4*)(orow + col) = o;
        }
    }
}

extern "C" void kernel_launch(void* const* d_in, const int* in_sizes, int n_in,
                              void* d_out, int out_size, void* d_ws, size_t ws_size,
                              hipStream_t stream)
{
    const float* x     = (const float*)d_in[0];
    const float* Wr    = (const float*)d_in[1];
    const float* br    = (const float*)d_in[2];
    const float* Wo    = (const float*)d_in[3];
    const float* bo    = (const float*)d_in[4];
    const float* gamma = (const float*)d_in[5];
    const float* beta  = (const float*)d_in[6];
    float* out = (float*)d_out;

    const int B = in_sizes[0] / Dh;       // 32768
    dim3 grid(B / RPB);                   // 4096 blocks
    phase_fused<<<grid, BLOCK, 0, stream>>>(x, Wr, br, Wo, bo, gamma, beta, out);
}

// Round 2
// 429.125 us; speedup vs baseline: 1.6973x; 1.6973x over previous
//
#include <hip/hip_runtime.h>
#include <math.h>

// PhaseRefinement fused kernel, v2: plane-split waves, x staged in LDS
// (double-buffered, global_load_lds), W read from global (L2-resident).
// out = x + LN(c*x)*gamma + beta; LN(c*x) collapses to
//   normed = gamma*(alpha*x - alpha*mu) + beta,
//   alpha = c*rsqrt(c^2*var + 1e-5), mu/var = plain row stats of x.

constexpr int Dh     = 4096;
constexpr int Ph     = 16;
constexpr int NPL    = 32;          // 2*P dots per row
constexpr int CHUNK  = 256;         // columns per LDS x-chunk
constexpr int NCHUNK = Dh / CHUNK;  // 16
constexpr int RPB    = 8;           // rows per block
constexpr int NW     = 8;           // waves per block
constexpr int PPW    = NPL / NW;    // 4 planes per wave
constexpr int BLOCK  = 64 * NW;     // 512

__global__ __launch_bounds__(BLOCK, 4)
void phase_fused(const float* __restrict__ x,
                 const float* __restrict__ Wr,
                 const float* __restrict__ br,
                 const float* __restrict__ Wo,
                 const float* __restrict__ bo,
                 const float* __restrict__ gamma,
                 const float* __restrict__ beta,
                 float* __restrict__ out)
{
    __shared__ float x_lds[2][RPB][CHUNK];   // 16 KB double-buffered x chunk
    __shared__ float dots_lds[RPB][NPL];
    __shared__ float stats_lds[RPB][2];
    __shared__ float scale_lds[RPB][2];

    const int t    = threadIdx.x;
    const int wv   = t >> 6;
    const int lane = t & 63;
    const size_t rowbase = (size_t)blockIdx.x * RPB;

    // This wave's 4 plane rows of W (planes wv*4 .. wv*4+3; 0..15 refine, 16..31 out)
    const float* wrow[PPW];
#pragma unroll
    for (int p = 0; p < PPW; ++p) {
        const int q = wv * PPW + p;
        wrow[p] = (q < Ph) ? (Wr + (size_t)q * Dh) : (Wo + (size_t)(q - Ph) * Dh);
    }

    // Wave wv stages row wv's chunks: 64 lanes x 16 B = 1 KB = 256 floats.
    const float* xsrc = x + (rowbase + wv) * (size_t)Dh + lane * 4;

    float acc[RPB][PPW];
#pragma unroll
    for (int r = 0; r < RPB; ++r)
#pragma unroll
        for (int p = 0; p < PPW; ++p) acc[r][p] = 0.f;
    float sx = 0.f, sxx = 0.f;

    // Prologue: stage chunk 0 into buffer 0.
    __builtin_amdgcn_global_load_lds(
        (const __attribute__((address_space(1))) void*)(xsrc),
        (__attribute__((address_space(3))) void*)(&x_lds[0][wv][0]), 16, 0, 0);

    for (int c = 0; c < NCHUNK; ++c) {
        const int cur = c & 1;
        __syncthreads();   // drains vmcnt(0): stage c complete; prev compute done
        if (c + 1 < NCHUNK) {
            // Prefetch next chunk; its latency hides under this chunk's compute,
            // drained by the NEXT iteration's __syncthreads.
            __builtin_amdgcn_global_load_lds(
                (const __attribute__((address_space(1))) void*)(xsrc + (size_t)(c + 1) * CHUNK),
                (__attribute__((address_space(3))) void*)(&x_lds[cur ^ 1][wv][0]), 16, 0, 0);
        }

        // W for this chunk, straight from global (L2-hot, coalesced 16 B/lane).
        float4 w4[PPW];
#pragma unroll
        for (int p = 0; p < PPW; ++p)
            w4[p] = *(const float4*)(wrow[p] + c * CHUNK + lane * 4);

        // x rows from LDS (contiguous 16 B/lane, conflict-free).
        float4 x4[RPB];
#pragma unroll
        for (int r = 0; r < RPB; ++r)
            x4[r] = *(const float4*)&x_lds[cur][r][lane * 4];

        // Row stats: wave wv owns row wv. Separate uniform ds_read (avoids
        // runtime-indexing the x4 register array -> scratch).
        float4 xs = *(const float4*)&x_lds[cur][wv][lane * 4];
        sx  += xs.x + xs.y + xs.z + xs.w;
        sxx += xs.x*xs.x + xs.y*xs.y + xs.z*xs.z + xs.w*xs.w;

#pragma unroll
        for (int r = 0; r < RPB; ++r)
#pragma unroll
            for (int p = 0; p < PPW; ++p)
                acc[r][p] += x4[r].x*w4[p].x + x4[r].y*w4[p].y
                           + x4[r].z*w4[p].z + x4[r].w*w4[p].w;
    }

    // Butterfly-reduce each accumulator across the 64 lanes.
#pragma unroll
    for (int r = 0; r < RPB; ++r)
#pragma unroll
        for (int p = 0; p < PPW; ++p) {
            float v = acc[r][p];
#pragma unroll
            for (int m = 1; m < 64; m <<= 1) v += __shfl_xor(v, m, 64);
            if (lane == 0) dots_lds[r][wv * PPW + p] = v;
        }
#pragma unroll
    for (int m = 1; m < 64; m <<= 1) {
        sx  += __shfl_xor(sx, m, 64);
        sxx += __shfl_xor(sxx, m, 64);
    }
    if (lane == 0) { stats_lds[wv][0] = sx; stats_lds[wv][1] = sxx; }
    __syncthreads();

    // Per-row scalar phase (8 threads, one per row).
    if (t < RPB) {
        const int r = t;
        float s = 0.f;
#pragma unroll
        for (int p = 0; p < Ph; ++p) {
            float rp = tanhf(dots_lds[r][p]      + br[p]);
            float op = tanhf(dots_lds[r][Ph + p] + bo[p]);
            s += cosf((rp - op) * 3.14159265358979323846f);
        }
        float gain = log1pf(expf(s * (1.f / Ph) + 0.5f));   // softplus(resonance+0.5)
        float cm   = s * gain * (1.f / Ph);                  // per-row scalar c
        float mu   = stats_lds[r][0] * (1.f / Dh);
        float var  = stats_lds[r][1] * (1.f / Dh) - mu * mu;
        var = fmaxf(var, 0.f);
        float rstd  = rsqrtf(cm * cm * var + 1e-5f);
        float alpha = cm * rstd;
        scale_lds[r][0] = alpha;
        scale_lds[r][1] = alpha * mu;
    }
    __syncthreads();

    // Phase B: wave wv writes row wv. x re-read is L2-hot (verified R1:
    // FETCH_SIZE ~= x read once).
    {
        const float alpha = scale_lds[wv][0];
        const float am    = scale_lds[wv][1];
        const float* xr = x   + (rowbase + wv) * (size_t)Dh;
        float* orow     = out + (rowbase + wv) * (size_t)Dh;
#pragma unroll
        for (int i = 0; i < Dh / (64 * 4); ++i) {   // 16 iterations
            const int col = i * 256 + lane * 4;
            float4 xv = *(const float4*)(xr + col);
            float4 g  = *(const float4*)(gamma + col);
            float4 bb = *(const float4*)(beta + col);
            float4 o;
            o.x = xv.x + g.x * (alpha * xv.x - am) + bb.x;
            o.y = xv.y + g.y * (alpha * xv.y - am) + bb.y;
            o.z = xv.z + g.z * (alpha * xv.z - am) + bb.z;
            o.w = xv.w + g.w * (alpha * xv.w - am) + bb.w;
            *(float4*)(orow + col) = o;
        }
    }
}

extern "C" void kernel_launch(void* const* d_in, const int* in_sizes, int n_in,
                              void* d_out, int out_size, void* d_ws, size_t ws_size,
                              hipStream_t stream)
{
    const float* x     = (const float*)d_in[0];
    const float* Wr    = (const float*)d_in[1];
    const float* br    = (const float*)d_in[2];
    const float* Wo    = (const float*)d_in[3];
    const float* bo    = (const float*)d_in[4];
    const float* gamma = (const float*)d_in[5];
    const float* beta  = (const float*)d_in[6];
    float* out = (float*)d_out;

    const int B = in_sizes[0] / Dh;       // 32768
    dim3 grid(B / RPB);                   // 4096 blocks
    phase_fused<<<grid, BLOCK, 0, stream>>>(x, Wr, br, Wo, bo, gamma, beta, out);
}